// Round 1
// baseline (586.214 us; speedup 1.0000x reference)
//
#include <hip/hip_runtime.h>
#include <stdint.h>

// Problem constants
#define B_SZ   32
#define NIN    2312
#define NHID   512
#define NOUT   10
#define T_SZ   350
#define NW32   73                 // ceil(2312/32) bitmask words per column
#define NW64   8                  // 512/64 ballot words per hidden column

// psp (SRM) kernel eps[n] = CS * n * DS^n, DS = exp(-0.1), CS = e/10
#define DS_D   0.9048374180359595
#define CS_D   0.2718281828459045
#define D100_D 4.5399929762484854e-05   // exp(-10) = DS^100
// refractory: ref recurrence in fp32 exactly like the reference scan
#define DREF_F 0.36787944117144233f     // exp(-1)
#define CREF_F -54.36563656918091f      // -2*10*e

// ---------------------------------------------------------------------------
// K1: bitpack spikeInput [B, NIN, T] -> bits1[(b*T + t)*73 + w]
// block: (w, b), 384 threads = t. Reads coalesced along t.
__global__ __launch_bounds__(384) void k1_bitpack(const float* __restrict__ x,
                                                  uint32_t* __restrict__ bits1) {
    const int w = blockIdx.x;   // 0..72
    const int b = blockIdx.y;   // 0..31
    const int t = threadIdx.x;
    if (t >= T_SZ) return;
    uint32_t bits = 0;
    const float* p = x + ((size_t)(b * NIN + (w << 5))) * T_SZ + t;
#pragma unroll
    for (int j = 0; j < 32; ++j) {
        int i = (w << 5) + j;
        if (i < NIN) {
            if (p[(size_t)j * T_SZ] > 0.5f) bits |= (1u << j);
        }
    }
    bits1[(size_t)(b * T_SZ + t) * NW32 + w] = bits;
}

// ---------------------------------------------------------------------------
// K2: transpose W1 [512, 2312] -> W1t [2312, 512]
__global__ void k2_transpose(const float* __restrict__ W1, float* __restrict__ W1t) {
    __shared__ float tile[32][33];
    const int i0 = blockIdx.x * 32, o0 = blockIdx.y * 32;
    const int tx = threadIdx.x, ty = threadIdx.y;  // 32 x 8
#pragma unroll
    for (int r = 0; r < 4; ++r) {
        int o = o0 + ty + r * 8, i = i0 + tx;
        if (o < NHID && i < NIN) tile[ty + r * 8][tx] = W1[(size_t)o * NIN + i];
    }
    __syncthreads();
#pragma unroll
    for (int r = 0; r < 4; ++r) {
        int i = i0 + ty + r * 8, o = o0 + tx;
        if (i < NIN && o < NHID) W1t[(size_t)i * NHID + o] = tile[tx][ty + r * 8];
    }
}

// ---------------------------------------------------------------------------
// K3: sparse dense1. One block per (b,t) column. z1t[(b*T+t)*512 + o].
// Uniform bitmask walk (no divergence, deterministic order), float2 per thread.
__global__ __launch_bounds__(256) void k3_dense1(const uint32_t* __restrict__ bits1,
                                                 const float* __restrict__ W1t,
                                                 float* __restrict__ z1t) {
    __shared__ uint32_t words[NW32];
    const int bt = blockIdx.x;   // b*350 + t
    if (threadIdx.x < NW32) words[threadIdx.x] = bits1[(size_t)bt * NW32 + threadIdx.x];
    __syncthreads();
    const int tid = threadIdx.x;
    float2 acc = make_float2(0.f, 0.f);
    for (int w = 0; w < NW32; ++w) {
        uint32_t m = words[w];
        while (m) {
            int j = __builtin_ctz(m);
            m &= m - 1;
            const float2* row = (const float2*)(W1t + (size_t)((w << 5) + j) * NHID);
            float2 v = row[tid];
            acc.x += v.x;
            acc.y += v.y;
        }
    }
    ((float2*)(z1t + (size_t)bt * NHID))[tid] = acc;
}

// ---------------------------------------------------------------------------
// K4: fused psp-IIR (fp64, exact truncated-FIR via delayed tail correction)
//     + refractory spike scan (fp32, replicates reference recurrence).
// 256 blocks x 64 threads: block = (b, oc), lane = o within 64-chunk.
// Emits s1 as ballot masks: s1bits[(b*8 + oc)*T + t].
__global__ __launch_bounds__(64) void k4_fir_scan1(const float* __restrict__ z1t,
                                                   uint64_t* __restrict__ s1bits) {
    const int lane = threadIdx.x;
    const int b = blockIdx.x >> 3;
    const int oc = blockIdx.x & 7;
    const int o = (oc << 6) + lane;
    double A = 0.0, Bs = 0.0, A2 = 0.0, Bs2 = 0.0;
    float ra = 0.0f, rb = 0.0f;
    const double TAIL = D100_D * CS_D;
    const float* base = z1t + (size_t)b * T_SZ * NHID + o;
    uint64_t* outp = s1bits + (size_t)(b * NW64 + oc) * T_SZ;
    for (int t = 0; t < T_SZ; ++t) {
        float x = base[(size_t)t * NHID];
        float xd = (t >= 100) ? base[(size_t)(t - 100) * NHID] : 0.0f;
        // main alpha IIR (order: Bs uses old A)
        Bs = DS_D * Bs + DS_D * A;
        A = DS_D * A + (double)x;
        // delayed-input IIR for the >=100-tap tail
        Bs2 = DS_D * Bs2 + DS_D * A2;
        A2 = DS_D * A2 + (double)xd;
        double y = CS_D * Bs - TAIL * (Bs2 + 100.0 * A2);
        // refractory scan, fp32, exactly the reference recurrence
        float u = (float)y + CREF_F * rb;
        float s = (u >= 10.0f) ? 1.0f : 0.0f;
        float ra_new = DREF_F * ra + s;
        float rb_new = DREF_F * rb + DREF_F * ra;
        ra = ra_new;
        rb = rb_new;
        uint64_t m = __ballot(s != 0.0f);
        if (lane == 0) outp[t] = m;
    }
}

// ---------------------------------------------------------------------------
// K5: sparse dense2: z2t[t*320 + b*10+o] = sum_c s1[b,c,t] * W2[o,c]
__global__ __launch_bounds__(256) void k5_dense2(const uint64_t* __restrict__ s1bits,
                                                 const float* __restrict__ W2,
                                                 float* __restrict__ z2t) {
    __shared__ float W2s[NHID * NOUT];  // [c][o], 20 KB
    for (int k = threadIdx.x; k < NHID * NOUT; k += 256) {
        int c = k / NOUT, o = k - c * NOUT;
        W2s[k] = W2[(size_t)o * NHID + c];
    }
    __syncthreads();
    int idx = blockIdx.x * 256 + threadIdx.x;   // t*320 + bo
    if (idx >= T_SZ * B_SZ * NOUT) return;
    int t = idx / (B_SZ * NOUT);
    int bo = idx - t * (B_SZ * NOUT);
    int b = bo / NOUT;
    int o = bo - b * NOUT;
    float acc = 0.f;
    const uint64_t* bp = s1bits + (size_t)b * NW64 * T_SZ + t;
#pragma unroll
    for (int wv = 0; wv < NW64; ++wv) {
        uint64_t m = bp[(size_t)wv * T_SZ];
        while (m) {
            int j = __builtin_ctzll(m);
            m &= m - 1;
            acc += W2s[((wv << 6) + j) * NOUT + o];
        }
    }
    z2t[idx] = acc;
}

// ---------------------------------------------------------------------------
// K6: fused psp-IIR + refractory scan for layer 2; writes d_out [B, NOUT, T].
__global__ __launch_bounds__(64) void k6_fir_scan2(const float* __restrict__ z2t,
                                                   float* __restrict__ out) {
    const int bo = blockIdx.x * 64 + threadIdx.x;  // 0..319
    double A = 0.0, Bs = 0.0, A2 = 0.0, Bs2 = 0.0;
    float ra = 0.0f, rb = 0.0f;
    const double TAIL = D100_D * CS_D;
    float* op = out + (size_t)bo * T_SZ;
    for (int t = 0; t < T_SZ; ++t) {
        float x = z2t[(size_t)t * (B_SZ * NOUT) + bo];
        float xd = (t >= 100) ? z2t[(size_t)(t - 100) * (B_SZ * NOUT) + bo] : 0.0f;
        Bs = DS_D * Bs + DS_D * A;
        A = DS_D * A + (double)x;
        Bs2 = DS_D * Bs2 + DS_D * A2;
        A2 = DS_D * A2 + (double)xd;
        double y = CS_D * Bs - TAIL * (Bs2 + 100.0 * A2);
        float u = (float)y + CREF_F * rb;
        float s = (u >= 10.0f) ? 1.0f : 0.0f;
        float ra_new = DREF_F * ra + s;
        float rb_new = DREF_F * rb + DREF_F * ra;
        ra = ra_new;
        rb = rb_new;
        op[t] = s;
    }
}

// ---------------------------------------------------------------------------
extern "C" void kernel_launch(void* const* d_in, const int* in_sizes, int n_in,
                              void* d_out, int out_size, void* d_ws, size_t ws_size,
                              hipStream_t stream) {
    const float* spikeInput = (const float*)d_in[0];  // [32, 2312, 350]
    const float* W1 = (const float*)d_in[1];          // [512, 2312]
    const float* W2 = (const float*)d_in[2];          // [10, 512]
    float* out = (float*)d_out;                       // [32, 10, 350]

    char* ws = (char*)d_ws;
    // workspace layout (all 256B-aligned)
    float* W1t = (float*)(ws + 0);                        //  4,734,976 B
    uint32_t* bits1 = (uint32_t*)(ws + 4734976);          //  3,270,400 B
    float* z1t = (float*)(ws + 8005376);                  // 22,937,600 B
    uint64_t* s1bits = (uint64_t*)(ws + 30942976);        //    716,800 B
    float* z2t = (float*)(ws + 31659776);                 //    448,000 B
    // total: 32,107,776 B

    k1_bitpack<<<dim3(NW32, B_SZ), 384, 0, stream>>>(spikeInput, bits1);
    k2_transpose<<<dim3(73, 16), dim3(32, 8), 0, stream>>>(W1, W1t);
    k3_dense1<<<B_SZ * T_SZ, 256, 0, stream>>>(bits1, W1t, z1t);
    k4_fir_scan1<<<B_SZ * NW64, 64, 0, stream>>>(z1t, s1bits);
    k5_dense2<<<(T_SZ * B_SZ * NOUT + 255) / 256, 256, 0, stream>>>(s1bits, W2, z2t);
    k6_fir_scan2<<<(B_SZ * NOUT) / 64, 64, 0, stream>>>(z2t, out);
}

// Round 2
// 380.239 us; speedup vs baseline: 1.5417x; 1.5417x over previous
//
#include <hip/hip_runtime.h>
#include <stdint.h>

// Problem constants
#define B_SZ   32
#define NIN    2312
#define NHID   512
#define NOUT   10
#define T_SZ   350
#define NW32   73                 // ceil(2312/32) bitmask words per input column
#define NW64   8                  // 512/64 ballot words per hidden column
#define NHALF  256                // output half-width for L2-resident W1

// psp (SRM) kernel eps[n] = CS * n * DS^n, DS = exp(-0.1), CS = e/10
#define DS_D   0.9048374180359595
#define CS_D   0.2718281828459045
#define D100_D 4.5399929762484854e-05   // exp(-10) = DS^100
// refractory recurrence in fp32, exactly like the reference scan
#define DREF_F 0.36787944117144233f     // exp(-1)
#define CREF_F -54.36563656918091f      // -2*10*e

#define NPF 14                    // prefetch ring depth (350 = 14*25)

// ---------------------------------------------------------------------------
// K1: bitpack spikeInput [B, NIN, T] -> bits1[(b*T + t)*73 + w]
__global__ __launch_bounds__(384) void k1_bitpack(const float* __restrict__ x,
                                                  uint32_t* __restrict__ bits1) {
    const int w = blockIdx.x;   // 0..72
    const int b = blockIdx.y;   // 0..31
    const int t = threadIdx.x;
    if (t >= T_SZ) return;
    uint32_t bits = 0;
    const float* p = x + ((size_t)(b * NIN + (w << 5))) * T_SZ + t;
#pragma unroll
    for (int j = 0; j < 32; ++j) {
        int i = (w << 5) + j;
        if (i < NIN) {
            if (p[(size_t)j * T_SZ] > 0.5f) bits |= (1u << j);
        }
    }
    bits1[(size_t)(b * T_SZ + t) * NW32 + w] = bits;
}

// ---------------------------------------------------------------------------
// K2: pack W1 [512, 2312] -> W1s[h][i][256]  (h = o>>8, half-split for L2)
__global__ void k2_pack(const float* __restrict__ W1, float* __restrict__ W1s) {
    __shared__ float tile[32][33];
    const int i0 = blockIdx.x * 32, o0 = blockIdx.y * 32;
    const int tx = threadIdx.x, ty = threadIdx.y;  // 32 x 8
#pragma unroll
    for (int r = 0; r < 4; ++r) {
        int o = o0 + ty + r * 8, i = i0 + tx;
        if (i < NIN) tile[ty + r * 8][tx] = W1[(size_t)o * NIN + i];
    }
    __syncthreads();
#pragma unroll
    for (int r = 0; r < 4; ++r) {
        int i = i0 + ty + r * 8, o = o0 + tx;   // o in [o0, o0+32), single half
        if (i < NIN)
            W1s[((size_t)(o >> 8) * NIN + i) * NHALF + (o & 255)] = tile[tx][ty + r * 8];
    }
}

// ---------------------------------------------------------------------------
// K3: sparse dense1, half-split. Block = (bt, h). Compacts active indices,
// then 4 waves each stride over rows with one dwordx4/lane (1024B row half).
// Writes z1ct[(b*8+oc)*350 + t][64] (channel-chunk-major for k4 streaming).
__global__ __launch_bounds__(256) void k3_dense1(const uint32_t* __restrict__ bits1,
                                                 const float* __restrict__ W1s,
                                                 float* __restrict__ z1ct) {
    __shared__ uint32_t words[NW32];
    __shared__ uint16_t pfx[128];
    __shared__ uint16_t idxbuf[NIN];
    __shared__ float red[3][NHALF];
    __shared__ float fin[NHALF];

    const int bt = blockIdx.x;          // b*350 + t
    const int h = blockIdx.y;           // 0 or 1
    const int tid = threadIdx.x;

    if (tid < 128) pfx[tid] = 0;
    if (tid < NW32) words[tid] = bits1[(size_t)bt * NW32 + tid];
    __syncthreads();
    if (tid < NW32) pfx[tid + 1] = (uint16_t)__popc(words[tid]);
    __syncthreads();
    // Hillis-Steele inclusive scan over pfx[0..127]
    for (int off = 1; off < 128; off <<= 1) {
        uint16_t v = 0;
        if (tid < 128 && tid >= off) v = pfx[tid - off];
        __syncthreads();
        if (tid < 128) pfx[tid] += v;
        __syncthreads();
    }
    // pfx[w] is now the exclusive prefix for word w; pfx[73] = total count
    if (tid < NW32) {
        uint32_t m = words[tid];
        int p = pfx[tid];
        while (m) {
            int j = __builtin_ctz(m);
            m &= m - 1;
            idxbuf[p++] = (uint16_t)((tid << 5) + j);
        }
    }
    __syncthreads();
    const int ntot = pfx[NW32];

    const int g = tid >> 6;             // wave id 0..3
    const int l = tid & 63;
    const float* Wh = W1s + (size_t)h * NIN * NHALF;
    float4 acc = make_float4(0.f, 0.f, 0.f, 0.f);
    for (int r = g; r < ntot; r += 4) {
        int row = idxbuf[r];
        const float4* rp = (const float4*)(Wh + (size_t)row * NHALF);
        float4 v = rp[l];
        acc.x += v.x; acc.y += v.y; acc.z += v.z; acc.w += v.w;
    }
    if (g > 0) ((float4*)red[g - 1])[l] = acc;
    __syncthreads();
    if (g == 0) {
        float4 a1 = ((float4*)red[0])[l];
        float4 a2 = ((float4*)red[1])[l];
        float4 a3 = ((float4*)red[2])[l];
        acc.x = ((acc.x + a1.x) + a2.x) + a3.x;
        acc.y = ((acc.y + a1.y) + a2.y) + a3.y;
        acc.z = ((acc.z + a1.z) + a2.z) + a3.z;
        acc.w = ((acc.w + a1.w) + a2.w) + a3.w;
        ((float4*)fin)[l] = acc;
    }
    __syncthreads();
    // scatter to channel-chunk-major layout, coalesced per wave
    const int och = (h << 8) + tid;     // global hidden channel
    const int oc = och >> 6, lane = och & 63;
    const int b = bt / T_SZ, t = bt - b * T_SZ;
    z1ct[((size_t)(b * NW64 + oc) * T_SZ + t) * 64 + lane] = fin[tid];
}

// ---------------------------------------------------------------------------
// K4: fused psp-IIR (fp64, exact truncated FIR via delayed tail) + refractory
// spike scan (fp32 = reference recurrence). 14-deep register prefetch rings.
// Block = (b, oc), 64 lanes = channels. Emits ballots s1bits[(b*8+oc)*T + t].
__global__ __launch_bounds__(64) void k4_fir_scan1(const float* __restrict__ z1ct,
                                                   uint64_t* __restrict__ s1bits) {
    const int lane = threadIdx.x;
    const int bc = blockIdx.x;          // b*8 + oc
    const float* base = z1ct + (size_t)bc * T_SZ * 64 + lane;
    uint64_t* outp = s1bits + (size_t)bc * T_SZ;
    double A = 0.0, Bs = 0.0, A2 = 0.0, Bs2 = 0.0;
    float ra = 0.0f, rb = 0.0f;
    const double TAIL = D100_D * CS_D;
    float xb[NPF], xdb[NPF];
#pragma unroll
    for (int i = 0; i < NPF; ++i) {
        xb[i] = base[(size_t)i * 64];
        xdb[i] = 0.0f;
    }
    for (int t0 = 0; t0 < T_SZ; t0 += NPF) {
#pragma unroll
        for (int i = 0; i < NPF; ++i) {
            const int t = t0 + i;
            float x = xb[i], xd = xdb[i];
            const int tn = t + NPF;
            xb[i] = (tn < T_SZ) ? base[(size_t)tn * 64] : 0.0f;
            const int td = tn - 100;
            xdb[i] = (td >= 0) ? base[(size_t)td * 64] : 0.0f;
            Bs = DS_D * Bs + DS_D * A;
            A = DS_D * A + (double)x;
            Bs2 = DS_D * Bs2 + DS_D * A2;
            A2 = DS_D * A2 + (double)xd;
            double y = CS_D * Bs - TAIL * (Bs2 + 100.0 * A2);
            float u = (float)y + CREF_F * rb;
            float s = (u >= 10.0f) ? 1.0f : 0.0f;
            float ran = DREF_F * ra + s;
            float rbn = DREF_F * rb + DREF_F * ra;
            ra = ran; rb = rbn;
            uint64_t mball = __ballot(s != 0.0f);
            if (lane == 0) outp[t] = mball;
        }
    }
}

// ---------------------------------------------------------------------------
// K5: sparse dense2: z2t[t*320 + b*10+o] = sum_c s1[b,c,t] * W2[o,c]
__global__ __launch_bounds__(256) void k5_dense2(const uint64_t* __restrict__ s1bits,
                                                 const float* __restrict__ W2,
                                                 float* __restrict__ z2t) {
    __shared__ float W2s[NHID * NOUT];  // [c][o], 20 KB
    for (int k = threadIdx.x; k < NHID * NOUT; k += 256) {
        int c = k / NOUT, o = k - c * NOUT;
        W2s[k] = W2[(size_t)o * NHID + c];
    }
    __syncthreads();
    int idx = blockIdx.x * 256 + threadIdx.x;   // t*320 + bo
    if (idx >= T_SZ * B_SZ * NOUT) return;
    int t = idx / (B_SZ * NOUT);
    int bo = idx - t * (B_SZ * NOUT);
    int b = bo / NOUT;
    int o = bo - b * NOUT;
    float acc = 0.f;
    const uint64_t* bp = s1bits + (size_t)b * NW64 * T_SZ + t;
#pragma unroll
    for (int wv = 0; wv < NW64; ++wv) {
        uint64_t m = bp[(size_t)wv * T_SZ];
        while (m) {
            int j = __builtin_ctzll(m);
            m &= m - 1;
            acc += W2s[((wv << 6) + j) * NOUT + o];
        }
    }
    z2t[idx] = acc;
}

// ---------------------------------------------------------------------------
// K6: fused psp-IIR + refractory scan, layer 2, with prefetch rings.
// Writes d_out [B, NOUT, T].
__global__ __launch_bounds__(64) void k6_fir_scan2(const float* __restrict__ z2t,
                                                   float* __restrict__ out) {
    const int bo = blockIdx.x * 64 + threadIdx.x;  // 0..319
    const float* base = z2t + bo;                  // stride 320 floats over t
    double A = 0.0, Bs = 0.0, A2 = 0.0, Bs2 = 0.0;
    float ra = 0.0f, rb = 0.0f;
    const double TAIL = D100_D * CS_D;
    float* op = out + (size_t)bo * T_SZ;
    float xb[NPF], xdb[NPF];
#pragma unroll
    for (int i = 0; i < NPF; ++i) {
        xb[i] = base[(size_t)i * (B_SZ * NOUT)];
        xdb[i] = 0.0f;
    }
    for (int t0 = 0; t0 < T_SZ; t0 += NPF) {
#pragma unroll
        for (int i = 0; i < NPF; ++i) {
            const int t = t0 + i;
            float x = xb[i], xd = xdb[i];
            const int tn = t + NPF;
            xb[i] = (tn < T_SZ) ? base[(size_t)tn * (B_SZ * NOUT)] : 0.0f;
            const int td = tn - 100;
            xdb[i] = (td >= 0) ? base[(size_t)td * (B_SZ * NOUT)] : 0.0f;
            Bs = DS_D * Bs + DS_D * A;
            A = DS_D * A + (double)x;
            Bs2 = DS_D * Bs2 + DS_D * A2;
            A2 = DS_D * A2 + (double)xd;
            double y = CS_D * Bs - TAIL * (Bs2 + 100.0 * A2);
            float u = (float)y + CREF_F * rb;
            float s = (u >= 10.0f) ? 1.0f : 0.0f;
            float ran = DREF_F * ra + s;
            float rbn = DREF_F * rb + DREF_F * ra;
            ra = ran; rb = rbn;
            op[t] = s;
        }
    }
}

// ---------------------------------------------------------------------------
extern "C" void kernel_launch(void* const* d_in, const int* in_sizes, int n_in,
                              void* d_out, int out_size, void* d_ws, size_t ws_size,
                              hipStream_t stream) {
    const float* spikeInput = (const float*)d_in[0];  // [32, 2312, 350]
    const float* W1 = (const float*)d_in[1];          // [512, 2312]
    const float* W2 = (const float*)d_in[2];          // [10, 512]
    float* out = (float*)d_out;                       // [32, 10, 350]

    char* ws = (char*)d_ws;
    float* W1s = (float*)(ws + 0);                        //  4,734,976 B
    uint32_t* bits1 = (uint32_t*)(ws + 4734976);          //  3,270,400 B
    float* z1ct = (float*)(ws + 8005376);                 // 22,937,600 B
    uint64_t* s1bits = (uint64_t*)(ws + 30942976);        //    716,800 B
    float* z2t = (float*)(ws + 31659776);                 //    448,000 B
    // total: 32,107,776 B

    k1_bitpack<<<dim3(NW32, B_SZ), 384, 0, stream>>>(spikeInput, bits1);
    k2_pack<<<dim3(73, 16), dim3(32, 8), 0, stream>>>(W1, W1s);
    k3_dense1<<<dim3(B_SZ * T_SZ, 2), 256, 0, stream>>>(bits1, W1s, z1ct);
    k4_fir_scan1<<<B_SZ * NW64, 64, 0, stream>>>(z1ct, s1bits);
    k5_dense2<<<(T_SZ * B_SZ * NOUT + 255) / 256, 256, 0, stream>>>(s1bits, W2, z2t);
    k6_fir_scan2<<<(B_SZ * NOUT) / 64, 64, 0, stream>>>(z2t, out);
}